// Round 11
// baseline (61.221 us; speedup 1.0000x reference)
//
#include <hip/hip_runtime.h>
#include <math.h>

#define KW 11
#define HALO 10
#define TY 32
#define BATCH 32
#define HH 512
#define WW 512
#define OH 502
#define OW 502
#define NSX 8          // 8 strips x 64 cols
#define WPB 2          // independent waves per block (no __syncthreads)
#define NBX 4
#define NBY 16
#define NWAVE (BATCH * NBY * NSX)   // 4096
#define C3V 1.0e-4f
#define SW 80          // staged cols per row (64 + 16 halo), one v2f (a,b) each

typedef float v2f __attribute__((ext_vector_type(2)));

static __device__ __forceinline__ float rfl(float x) {
    return __int_as_float(__builtin_amdgcn_readfirstlane(__float_as_int(x)));
}

// 2 independent waves/block; each wave owns a 64-col strip, 44 rows through an
// 11-slot wave-private LDS ring of interleaved (a,b) rows.
// Half-phase-skewed software pipeline, distance-3 global prefetch:
//   phase p (row yr): WRITE row yr+1 (loaded 3 phases ago, vmcnt pre-drained)
//                     LOAD row yr+3 into the freed staging set
//                     v-conv + epilogue of row yr-1 (h carried in regs)
//                     h-conv of row yr (from W)
//                     RDWIN slot p+1 -> W (consumed NEXT phase; the per-phase
//                     branch bounds the scheduling region so reads can't sink)
__global__ __launch_bounds__(128) void ssim_strip_kernel(
    const float* __restrict__ in1,
    const float* __restrict__ in2,
    const float* __restrict__ win,
    double* __restrict__ partials)
{
    __shared__ v2f sh[WPB][KW][SW];   // 14080 B

    const int t = threadIdx.x;
    const int wid = t >> 6;
    const int lane = t & 63;
    const int strip = blockIdx.x * WPB + wid;
    const int x0 = strip * 64;
    const int y0 = blockIdx.y * TY;
    const int img = blockIdx.z;

    const int nx = min(64, OW - x0);     // 64, last strip 54
    const int ny = min(TY, OH - y0);     // 32, last y-strip 22
    const int rows = ny + HALO;          // 42 or 32

    // separable 1D gaussian; symmetric: g[j] == g[10-j] -> 6 unique splats
    v2f gp[6];
    {
        const float c = sqrtf(win[5 * KW + 5]);
        #pragma unroll
        for (int i = 0; i < 6; ++i) {
            const float w = rfl(win[i * KW + 5] / c);
            gp[i] = (v2f){w, w};
        }
    }
    #define GW(j) gp[(j) <= 5 ? (j) : 10 - (j)]

    const float maskf = (lane < nx) ? 1.f : 0.f;
    const bool stager = lane < 40;                    // 40 lanes x 2 cols = 80
    const int scol = min(x0 + 2 * lane, WW - 2);      // clamped: no OOB
    const float* b1 = in1 + (size_t)img * HH * WW;
    const float* b2 = in2 + (size_t)img * HH * WW;

    v2f* const mysh = &sh[wid][0][0];                 // slot stride = SW v2f

    // two staging sets: row r lives in set r&1 (A=even rows, B=odd rows;
    // roles re-aligned by a swap at each 11-phase chunk end)
    v2f vaA, vbA, vaB, vbB;

#define LOADR_A(q) { const int rq = min(y0 + (q), HH - 1);            \
    vaA = *(const v2f*)(b1 + (size_t)rq * WW + scol);                 \
    vbA = *(const v2f*)(b2 + (size_t)rq * WW + scol); }
#define LOADR_B(q) { const int rq = min(y0 + (q), HH - 1);            \
    vaB = *(const v2f*)(b1 + (size_t)rq * WW + scol);                 \
    vbB = *(const v2f*)(b2 + (size_t)rq * WW + scol); }
#define WRITES_A(slot) { if (stager)                                   \
    *(float4*)&mysh[(slot) * SW + 2 * lane] =                          \
        make_float4(vaA.x, vbA.x, vaA.y, vbA.y); }
#define WRITES_B(slot) { if (stager)                                   \
    *(float4*)&mysh[(slot) * SW + 2 * lane] =                          \
        make_float4(vaB.x, vbB.x, vaB.y, vbB.y); }

    v2f W[KW];
#define RDWIN(slot) { const v2f* rp = mysh + (slot) * SW + lane;       \
    _Pragma("unroll") for (int j = 0; j < KW; ++j) W[j] = rp[j]; }

    // vertical accumulators: (a,b) packed, (aa,bb) packed, ab scalar
    v2f accab[KW], accsq[KW];
    float acc4[KW];
    #pragma unroll
    for (int i = 0; i < KW; ++i) {
        accab[i] = (v2f){0.f, 0.f}; accsq[i] = (v2f){0.f, 0.f}; acc4[i] = 0.f;
    }

    // carried h-conv results of row yr-1 (zero-init: early phases masked)
    v2f hab = (v2f){0.f, 0.f}, hsq = (v2f){0.f, 0.f};
    float h4 = 0.f;

    double tsum = 0.0;

    // prologue: row 0 staged; SB=row1, SA=row2; W=row0 window
    LOADR_A(0); WRITES_A(0);
    LOADR_B(1);
    LOADR_A(2);
    RDWIN(0);

// phase p: SET = staging set holding row yr+1 (p even -> B, p odd -> A)
#define PHASE(p, SET) {                                                 \
    const int yr = cbase + (p);                                         \
    if (yr <= rows) {                                                   \
        /* 1) stage row yr+1 (its load is 3 phases old) */              \
        WRITES_##SET(((p) + 1) % KW);                                   \
        /* 2) reload the freed set with row yr+3 */                     \
        LOADR_##SET(yr + 3);                                            \
        /* 3) v-conv of row yr-1 (carried h); rotation index pe */      \
        {                                                               \
            const int pe = ((p) + 10) % KW;                             \
            _Pragma("unroll")                                           \
            for (int r = 0; r < KW; ++r) {                              \
                const int j = (r - pe + KW) % KW;                       \
                const v2f g = GW(10 - j);                               \
                if (j == 10) {                                          \
                    accab[r] = g * hab; accsq[r] = g * hsq;             \
                    acc4[r] = g.x * h4;                                 \
                } else {                                                \
                    accab[r] = __builtin_elementwise_fma(g, hab, accab[r]); \
                    accsq[r] = __builtin_elementwise_fma(g, hsq, accsq[r]); \
                    acc4[r] = fmaf(g.x, h4, acc4[r]);                   \
                }                                                       \
            }                                                           \
            /* 4) register pe completes -> output row (yr-1)-10 */      \
            const int yrv = yr - 1;                                     \
            const v2f mu = accab[pe];                                   \
            const v2f sq = __builtin_elementwise_fma(-mu, mu, accsq[pe]); \
            const float s12 = fmaf(-mu.x, mu.y, acc4[pe]);              \
            const float den = __builtin_amdgcn_sqrtf(fabsf(sq.x * sq.y)) + C3V; \
            const float s = (s12 + C3V) * __builtin_amdgcn_rcpf(den);   \
            const float m = ((unsigned)(yrv - HALO) < (unsigned)ny) ? maskf : 0.f; \
            csum = fmaf(s, m, csum);                                    \
        }                                                               \
        /* 5) h-conv of row yr from W -> carried h regs */              \
        {                                                               \
            v2f nab = (v2f){0.f, 0.f}, nsq = (v2f){0.f, 0.f};           \
            float n4 = 0.f;                                             \
            _Pragma("unroll")                                           \
            for (int j = 0; j < KW; ++j) {                              \
                const v2f ab = W[j];                                    \
                const v2f g = GW(j);                                    \
                const v2f gab = g * ab;                                 \
                nab = __builtin_elementwise_fma(g, ab, nab);            \
                nsq = __builtin_elementwise_fma(gab, ab, nsq);          \
                n4 = fmaf(gab.x, ab.y, n4);                             \
            }                                                           \
            hab = nab; hsq = nsq; h4 = n4;                              \
        }                                                               \
        /* 6) refill W with row yr+1 (slot written in step 1); consumed  \
              next phase -> ds_read latency covered across the branch */ \
        RDWIN(((p) + 1) % KW);                                          \
    }                                                                   \
}

    for (int c = 0; c < 4; ++c) {
        const int cbase = c * KW;
        float csum = 0.f;
        PHASE(0, B) PHASE(1, A) PHASE(2, B) PHASE(3, A) PHASE(4, B)
        PHASE(5, A) PHASE(6, B) PHASE(7, A) PHASE(8, B) PHASE(9, A)
        PHASE(10, B)
        tsum += (double)csum;
        // chunk parity fix: row-parity of "p even" flips each chunk -> swap sets
        { v2f tmp;
          tmp = vaA; vaA = vaB; vaB = tmp;
          tmp = vbA; vbA = vbB; vbB = tmp; }
    }
#undef PHASE
#undef LOADR_A
#undef LOADR_B
#undef WRITES_A
#undef WRITES_B
#undef RDWIN
#undef GW

    // per-wave deterministic reduction
    #pragma unroll
    for (int off = 32; off > 0; off >>= 1)
        tsum += __shfl_down(tsum, off, 64);
    if (lane == 0) {
        const int bid = (img * NBY + blockIdx.y) * NSX + strip;
        partials[bid] = tsum;
    }
}

// deterministic final reduce of the 4096 wave partials -> mean
__global__ __launch_bounds__(256) void ssim_reduce_kernel(
    const double* __restrict__ partials, float* __restrict__ out)
{
    __shared__ double sred[4];
    double s = 0.0;
    for (int i = threadIdx.x; i < NWAVE; i += 256) s += partials[i];
    #pragma unroll
    for (int off = 32; off > 0; off >>= 1)
        s += __shfl_down(s, off, 64);
    const int wid = threadIdx.x >> 6;
    const int lane = threadIdx.x & 63;
    if (lane == 0) sred[wid] = s;
    __syncthreads();
    if (threadIdx.x == 0) {
        const double total = sred[0] + sred[1] + sred[2] + sred[3];
        out[0] = (float)(total / ((double)BATCH * OH * OW));
    }
}

extern "C" void kernel_launch(void* const* d_in, const int* in_sizes, int n_in,
                              void* d_out, int out_size, void* d_ws, size_t ws_size,
                              hipStream_t stream) {
    const float* in1 = (const float*)d_in[0];
    const float* in2 = (const float*)d_in[1];
    const float* win = (const float*)d_in[2];
    float* out = (float*)d_out;
    double* partials = (double*)d_ws;   // 4096 doubles = 32 KB

    dim3 grid(NBX, NBY, BATCH);
    dim3 block(WPB * 64);
    ssim_strip_kernel<<<grid, block, 0, stream>>>(in1, in2, win, partials);
    ssim_reduce_kernel<<<1, 256, 0, stream>>>(partials, out);
}

// Round 12
// 53.257 us; speedup vs baseline: 1.1495x; 1.1495x over previous
//
#include <hip/hip_runtime.h>
#include <math.h>

#define KW 11
#define HALO 10
#define TY 32
#define BATCH 32
#define HH 512
#define WW 512
#define OH 502
#define OW 502
#define NSX 8          // 8 strips x 64 cols
#define WPB 2          // independent waves per block (no __syncthreads)
#define NBX 4
#define NBY 16
#define NWAVE (BATCH * NBY * NSX)   // 4096
#define C3V 1.0e-4f
#define SW 80          // staged cols per row (64 + 16 halo), one v2f (a,b) each

typedef float v2f __attribute__((ext_vector_type(2)));

static __device__ __forceinline__ float rfl(float x) {
    return __int_as_float(__builtin_amdgcn_readfirstlane(__float_as_int(x)));
}

// Forced packed-f32 ops (VOP3P). clang may scalarize __builtin_elementwise_fma
// on v2f; these guarantee 1 instruction per 2-lane op.
static __device__ __forceinline__ v2f pk_fma(v2f a, v2f b, v2f c) {
    v2f d;
    asm("v_pk_fma_f32 %0, %1, %2, %3" : "=v"(d) : "v"(a), "v"(b), "v"(c));
    return d;
}
static __device__ __forceinline__ v2f pk_mul(v2f a, v2f b) {
    v2f d;
    asm("v_pk_mul_f32 %0, %1, %2" : "=v"(d) : "v"(a), "v"(b));
    return d;
}

// 2 independent waves/block; each wave owns a 64-col strip, 44 rows through
// an 11-slot wave-private LDS ring of interleaved (a,b) rows.
// Phase body (consume-then-refill, proven R7 structure):
//   1) h-conv from window regs W (row yr)      [forced v_pk_*]
//   2) ds_write row yr+1 -> slot p+1   3) ds_read slot p+1 -> W
//   4) global prefetch row yr+2        5) v-conv + fused epilogue [forced v_pk_*]
__global__ __launch_bounds__(128) void ssim_strip_kernel(
    const float* __restrict__ in1,
    const float* __restrict__ in2,
    const float* __restrict__ win,
    double* __restrict__ partials)
{
    __shared__ v2f sh[WPB][KW][SW];   // 14080 B

    const int t = threadIdx.x;
    const int wid = t >> 6;
    const int lane = t & 63;
    const int strip = blockIdx.x * WPB + wid;
    const int x0 = strip * 64;
    const int y0 = blockIdx.y * TY;
    const int img = blockIdx.z;

    const int nx = min(64, OW - x0);     // 64, last strip 54
    const int ny = min(TY, OH - y0);     // 32, last y-strip 22

    // separable 1D gaussian; symmetric: g[j] == g[10-j] -> 6 unique weights.
    // gp[]: v2f splats (VGPR pairs, asm operands); gs[]: scalars (SGPR).
    v2f gp[6];
    float gs[6];
    {
        const float c = sqrtf(win[5 * KW + 5]);
        #pragma unroll
        for (int i = 0; i < 6; ++i) {
            const float w = rfl(win[i * KW + 5] / c);
            gs[i] = w;
            gp[i] = (v2f){w, w};
        }
    }
    #define GWI(j) ((j) <= 5 ? (j) : 10 - (j))

    const float maskf = (lane < nx) ? 1.f : 0.f;
    const bool stager = lane < 40;                    // 40 lanes x 2 cols = 80
    const int scol = min(x0 + 2 * lane, WW - 2);      // clamped: no OOB
    const float* b1 = in1 + (size_t)img * HH * WW;
    const float* b2 = in2 + (size_t)img * HH * WW;

    v2f* const mysh = &sh[wid][0][0];                 // slot stride = SW v2f

    v2f va, vb;
#define LOADR(q) { const int rq = min(y0 + (q), HH - 1);             \
    va = *(const v2f*)(b1 + (size_t)rq * WW + scol);                 \
    vb = *(const v2f*)(b2 + (size_t)rq * WW + scol); }
#define WRITES(slot) { if (stager)                                    \
    *(float4*)&mysh[(slot) * SW + 2 * lane] =                         \
        make_float4(va.x, vb.x, va.y, vb.y); }
#define RDWIN(slot) { const v2f* rp = mysh + (slot) * SW + lane;      \
    _Pragma("unroll") for (int j = 0; j < KW; ++j) W[j] = rp[j]; }

    // vertical accumulators: (a,b) packed, (aa,bb) packed, ab scalar
    v2f accab[KW], accsq[KW];
    float acc4[KW];
    #pragma unroll
    for (int i = 0; i < KW; ++i) {
        accab[i] = (v2f){0.f, 0.f}; accsq[i] = (v2f){0.f, 0.f}; acc4[i] = 0.f;
    }

    v2f W[KW];
    double tsum = 0.0;

    // prologue: row 0 staged + window loaded; row 1 in staging regs
    LOADR(0);
    WRITES(0);
    RDWIN(0);
    LOADR(1);

    for (int c = 0; c < 4; ++c) {        // 44 rows total, fixed
        float csum = 0.f;
        #pragma unroll
        for (int p = 0; p < KW; ++p) {
            const int yr = c * KW + p;

            // 1) horizontal 11-tap conv from W (row yr), forced packed
            v2f hab = (v2f){0.f, 0.f}, hsq = (v2f){0.f, 0.f};
            float h4 = 0.f;
            #pragma unroll
            for (int j = 0; j < KW; ++j) {
                const v2f ab = W[j];
                const v2f g = gp[GWI(j)];
                const v2f gab = pk_mul(g, ab);
                hab = pk_fma(g, ab, hab);
                hsq = pk_fma(gab, ab, hsq);
                h4 = fmaf(gab.x, ab.y, h4);
            }

            // 2) stage row yr+1 (loaded last phase) into slot p+1
            WRITES((p + 1) % KW);
            // 3) refill W with row yr+1's window (latency covered by step 5)
            RDWIN((p + 1) % KW);
            // 4) global prefetch row yr+2
            LOADR(yr + 2);

            // 5) vertical accumulate: slot j lives in register (j+p)%11;
            //    slot 10 is the first tap -> overwrite (no reset)
            #pragma unroll
            for (int r = 0; r < KW; ++r) {
                const int j = (r - p + KW) % KW;
                const int gi = GWI(10 - j);
                const v2f g = gp[gi];
                if (j == 10) {
                    accab[r] = pk_mul(g, hab);
                    accsq[r] = pk_mul(g, hsq);
                    acc4[r] = gs[gi] * h4;
                } else {
                    accab[r] = pk_fma(g, hab, accab[r]);
                    accsq[r] = pk_fma(g, hsq, accsq[r]);
                    acc4[r] = fmaf(gs[gi], h4, acc4[r]);
                }
            }
            // register p completes -> output row yr-10 (uniform branch)
            if (yr >= HALO) {
                const v2f mu = accab[p];
                const v2f sq = pk_fma(-mu, mu, accsq[p]);
                const float s12 = fmaf(-mu.x, mu.y, acc4[p]);
                const float den = __builtin_amdgcn_sqrtf(fabsf(sq.x * sq.y)) + C3V;
                const float s = (s12 + C3V) * __builtin_amdgcn_rcpf(den);
                const float m = ((yr - HALO) < ny) ? maskf : 0.f;
                csum = fmaf(s, m, csum);
            }
        }
        tsum += (double)csum;
    }
#undef LOADR
#undef WRITES
#undef RDWIN
#undef GWI

    // per-wave deterministic reduction
    #pragma unroll
    for (int off = 32; off > 0; off >>= 1)
        tsum += __shfl_down(tsum, off, 64);
    if (lane == 0) {
        const int bid = (img * NBY + blockIdx.y) * NSX + strip;
        partials[bid] = tsum;
    }
}

// deterministic final reduce of the 4096 wave partials -> mean
__global__ __launch_bounds__(256) void ssim_reduce_kernel(
    const double* __restrict__ partials, float* __restrict__ out)
{
    __shared__ double sred[4];
    double s = 0.0;
    for (int i = threadIdx.x; i < NWAVE; i += 256) s += partials[i];
    #pragma unroll
    for (int off = 32; off > 0; off >>= 1)
        s += __shfl_down(s, off, 64);
    const int wid = threadIdx.x >> 6;
    const int lane = threadIdx.x & 63;
    if (lane == 0) sred[wid] = s;
    __syncthreads();
    if (threadIdx.x == 0) {
        const double total = sred[0] + sred[1] + sred[2] + sred[3];
        out[0] = (float)(total / ((double)BATCH * OH * OW));
    }
}

extern "C" void kernel_launch(void* const* d_in, const int* in_sizes, int n_in,
                              void* d_out, int out_size, void* d_ws, size_t ws_size,
                              hipStream_t stream) {
    const float* in1 = (const float*)d_in[0];
    const float* in2 = (const float*)d_in[1];
    const float* win = (const float*)d_in[2];
    float* out = (float*)d_out;
    double* partials = (double*)d_ws;   // 4096 doubles = 32 KB

    dim3 grid(NBX, NBY, BATCH);
    dim3 block(WPB * 64);
    ssim_strip_kernel<<<grid, block, 0, stream>>>(in1, in2, win, partials);
    ssim_reduce_kernel<<<1, 256, 0, stream>>>(partials, out);
}

// Round 13
// 46.978 us; speedup vs baseline: 1.3032x; 1.1337x over previous
//
#include <hip/hip_runtime.h>
#include <math.h>

#define KW 11
#define HALO 10
#define TY 32
#define BATCH 32
#define HH 512
#define WW 512
#define OH 502
#define OW 502
#define NSX 8          // 8 strips x 64 cols
#define WPB 2          // independent waves per block (no __syncthreads)
#define NBX 4
#define NBY 16
#define NWAVE (BATCH * NBY * NSX)   // 4096
#define C3V 1.0e-4f
#define SW 80          // staged cols per row (64 + 16 halo), one v2f (a,b) each

typedef float v2f __attribute__((ext_vector_type(2)));

static __device__ __forceinline__ float rfl(float x) {
    return __int_as_float(__builtin_amdgcn_readfirstlane(__float_as_int(x)));
}

// 2 independent waves/block; each wave owns a 64-col strip, 44 rows through
// an 11-slot wave-private LDS ring of interleaved (a,b) rows.
// R7 phase structure + distance-2 global prefetch via dual staging sets:
//   phase p (row yr): 1) h-conv from W (row yr)
//                     2) ds_write row yr+1 -> slot p+1 (load is 2 phases old)
//                     3) ds_read slot p+1 -> W
//                     4) global load row yr+3 into the set freed by step 2
// Set parity is compile-time in the 11-phase unroll; sets swap at chunk end.
__global__ __launch_bounds__(128) void ssim_strip_kernel(
    const float* __restrict__ in1,
    const float* __restrict__ in2,
    const float* __restrict__ win,
    double* __restrict__ partials)
{
    __shared__ v2f sh[WPB][KW][SW];   // 14080 B

    const int t = threadIdx.x;
    const int wid = t >> 6;
    const int lane = t & 63;
    const int strip = blockIdx.x * WPB + wid;
    const int x0 = strip * 64;
    const int y0 = blockIdx.y * TY;
    const int img = blockIdx.z;

    const int nx = min(64, OW - x0);     // 64, last strip 54
    const int ny = min(TY, OH - y0);     // 32, last y-strip 22

    // separable 1D gaussian; symmetric: g[j] == g[10-j] -> 6 unique splats
    v2f gp[6];
    {
        const float c = sqrtf(win[5 * KW + 5]);
        #pragma unroll
        for (int i = 0; i < 6; ++i) {
            const float w = rfl(win[i * KW + 5] / c);
            gp[i] = (v2f){w, w};
        }
    }
    #define GW(j) gp[(j) <= 5 ? (j) : 10 - (j)]

    const float maskf = (lane < nx) ? 1.f : 0.f;
    const bool stager = lane < 40;                    // 40 lanes x 2 cols = 80
    const int scol = min(x0 + 2 * lane, WW - 2);      // clamped: no OOB
    const float* b1 = in1 + (size_t)img * HH * WW;
    const float* b2 = in2 + (size_t)img * HH * WW;

    v2f* const mysh = &sh[wid][0][0];                 // slot stride = SW v2f

    // dual staging sets: at phase p (even->A, odd->B) the set holds row yr+1
    v2f vaA, vbA, vaB, vbB;

#define LOADR_A(q) { const int rq = min(y0 + (q), HH - 1);            \
    vaA = *(const v2f*)(b1 + (size_t)rq * WW + scol);                 \
    vbA = *(const v2f*)(b2 + (size_t)rq * WW + scol); }
#define LOADR_B(q) { const int rq = min(y0 + (q), HH - 1);            \
    vaB = *(const v2f*)(b1 + (size_t)rq * WW + scol);                 \
    vbB = *(const v2f*)(b2 + (size_t)rq * WW + scol); }
#define WRITES_A(slot) { if (stager)                                   \
    *(float4*)&mysh[(slot) * SW + 2 * lane] =                          \
        make_float4(vaA.x, vbA.x, vaA.y, vbA.y); }
#define WRITES_B(slot) { if (stager)                                   \
    *(float4*)&mysh[(slot) * SW + 2 * lane] =                          \
        make_float4(vaB.x, vbB.x, vaB.y, vbB.y); }
#define RDWIN(slot) { const v2f* rp = mysh + (slot) * SW + lane;       \
    _Pragma("unroll") for (int j = 0; j < KW; ++j) W[j] = rp[j]; }

    // vertical accumulators: (a,b) packed, (aa,bb) packed, ab scalar
    v2f accab[KW], accsq[KW];
    float acc4[KW];
    #pragma unroll
    for (int i = 0; i < KW; ++i) {
        accab[i] = (v2f){0.f, 0.f}; accsq[i] = (v2f){0.f, 0.f}; acc4[i] = 0.f;
    }

    v2f W[KW];
    double tsum = 0.0;

    // prologue: row 0 staged + window loaded; row 1 -> set A, row 2 -> set B
    LOADR_A(0);
    WRITES_A(0);
    RDWIN(0);
    LOADR_A(1);
    LOADR_B(2);

#define PHASE(p, SET) {                                                 \
    const int yr = cbase + (p);                                         \
    /* 1) horizontal 11-tap conv from W (row yr), packed channels */    \
    v2f hab = (v2f){0.f, 0.f}, hsq = (v2f){0.f, 0.f};                   \
    float h4 = 0.f;                                                     \
    _Pragma("unroll")                                                   \
    for (int j = 0; j < KW; ++j) {                                      \
        const v2f ab = W[j];                                            \
        const v2f g = GW(j);                                            \
        const v2f gab = g * ab;                                         \
        hab = __builtin_elementwise_fma(g, ab, hab);                    \
        hsq = __builtin_elementwise_fma(gab, ab, hsq);                  \
        h4 = fmaf(gab.x, ab.y, h4);                                     \
    }                                                                   \
    /* 2) stage row yr+1 (loaded 2 phases ago) into slot p+1 */         \
    WRITES_##SET(((p) + 1) % KW);                                       \
    /* 3) refill W with row yr+1's window */                            \
    RDWIN(((p) + 1) % KW);                                              \
    /* 4) reload freed set with row yr+3 */                             \
    LOADR_##SET(yr + 3);                                                \
    /* 5) vertical accumulate: slot j -> register (j+p)%11; slot 10 */  \
    /*    is the first tap -> overwrite (no reset) */                   \
    _Pragma("unroll")                                                   \
    for (int r = 0; r < KW; ++r) {                                      \
        const int j = (r - (p) + KW) % KW;                              \
        const v2f g = GW(10 - j);                                       \
        if (j == 10) {                                                  \
            accab[r] = g * hab;                                         \
            accsq[r] = g * hsq;                                         \
            acc4[r] = g.x * h4;                                         \
        } else {                                                        \
            accab[r] = __builtin_elementwise_fma(g, hab, accab[r]);     \
            accsq[r] = __builtin_elementwise_fma(g, hsq, accsq[r]);     \
            acc4[r] = fmaf(g.x, h4, acc4[r]);                           \
        }                                                               \
    }                                                                   \
    /* 6) register p completes -> output row yr-10 (uniform branch) */  \
    if (yr >= HALO) {                                                   \
        const v2f mu = accab[(p)];                                      \
        const v2f sq = __builtin_elementwise_fma(-mu, mu, accsq[(p)]);  \
        const float s12 = fmaf(-mu.x, mu.y, acc4[(p)]);                 \
        const float den = __builtin_amdgcn_sqrtf(fabsf(sq.x * sq.y)) + C3V; \
        const float s = (s12 + C3V) * __builtin_amdgcn_rcpf(den);       \
        const float m = ((yr - HALO) < ny) ? maskf : 0.f;               \
        csum = fmaf(s, m, csum);                                        \
    }                                                                   \
}

    for (int c = 0; c < 4; ++c) {        // 44 rows total, fixed
        const int cbase = c * KW;
        float csum = 0.f;
        PHASE(0, A) PHASE(1, B) PHASE(2, A) PHASE(3, B) PHASE(4, A)
        PHASE(5, B) PHASE(6, A) PHASE(7, B) PHASE(8, A) PHASE(9, B)
        PHASE(10, A)
        tsum += (double)csum;
        // 11 phases flips parity: swap sets so "even phase -> A" stays true
        { v2f tmp;
          tmp = vaA; vaA = vaB; vaB = tmp;
          tmp = vbA; vbA = vbB; vbB = tmp; }
    }
#undef PHASE
#undef LOADR_A
#undef LOADR_B
#undef WRITES_A
#undef WRITES_B
#undef RDWIN
#undef GW

    // per-wave deterministic reduction
    #pragma unroll
    for (int off = 32; off > 0; off >>= 1)
        tsum += __shfl_down(tsum, off, 64);
    if (lane == 0) {
        const int bid = (img * NBY + blockIdx.y) * NSX + strip;
        partials[bid] = tsum;
    }
}

// deterministic final reduce of the 4096 wave partials -> mean
__global__ __launch_bounds__(256) void ssim_reduce_kernel(
    const double* __restrict__ partials, float* __restrict__ out)
{
    __shared__ double sred[4];
    double s = 0.0;
    for (int i = threadIdx.x; i < NWAVE; i += 256) s += partials[i];
    #pragma unroll
    for (int off = 32; off > 0; off >>= 1)
        s += __shfl_down(s, off, 64);
    const int wid = threadIdx.x >> 6;
    const int lane = threadIdx.x & 63;
    if (lane == 0) sred[wid] = s;
    __syncthreads();
    if (threadIdx.x == 0) {
        const double total = sred[0] + sred[1] + sred[2] + sred[3];
        out[0] = (float)(total / ((double)BATCH * OH * OW));
    }
}

extern "C" void kernel_launch(void* const* d_in, const int* in_sizes, int n_in,
                              void* d_out, int out_size, void* d_ws, size_t ws_size,
                              hipStream_t stream) {
    const float* in1 = (const float*)d_in[0];
    const float* in2 = (const float*)d_in[1];
    const float* win = (const float*)d_in[2];
    float* out = (float*)d_out;
    double* partials = (double*)d_ws;   // 4096 doubles = 32 KB

    dim3 grid(NBX, NBY, BATCH);
    dim3 block(WPB * 64);
    ssim_strip_kernel<<<grid, block, 0, stream>>>(in1, in2, win, partials);
    ssim_reduce_kernel<<<1, 256, 0, stream>>>(partials, out);
}